// Round 12
// baseline (254.872 us; speedup 1.0000x reference)
//
#include <hip/hip_runtime.h>

// ---------------------------------------------------------------------------
// GaussianDiffusionTrainer forward — blit + L3-resident RMW pipeline:
//   K_coef : coef[img] = {P[t-1], C[t-1]}          (all scattered gathers)
//   blit   : hipMemcpyAsync out <- x0              (platform's best read path)
//   K_fix  : out = out*Pt + diag(nrm)*Ct           (RMW; reads are L2/L3-warm)
// (8192, 3, 32, 32) fp32.  P,C = compile-time constexpr tables.
//
// R10 -> R11/R12: five kernel structures all hit the same ~2.2 TB/s wall
// while fillBuffer hits 6.8 TB/s write-only in the same captures ->
// compute-kernel READ path is the anomaly. The blit dispatch calibrates the
// machine's true read+write ceiling; the fixup kernel re-reads `out`
// immediately after the blit wrote it, so its reads hit L2/L3 not HBM.
// ---------------------------------------------------------------------------

constexpr int T_STEPS = 1000;
constexpr int BATCH   = 8192;
constexpr int N_ELEM  = BATCH * 3 * 32 * 32;          // 25,165,824
constexpr size_t N_BYTES = (size_t)N_ELEM * 4;        // 100,663,296
constexpr int COEF_BLOCKS = BATCH / 256;              // 32
constexpr int FIX_BLOCKS  = N_ELEM / 4 / 256;         // 24576 (1 block = 1 channel)

struct Tables { float P[T_STEPS]; float C[T_STEPS]; };

constexpr double csqrt_d(double x) {
    if (x <= 0.0) return 0.0;
    double scale = 1.0;
    while (x < 0.25) { x *= 4.0;  scale *= 0.5; }
    while (x >= 1.0) { x *= 0.25; scale *= 2.0; }
    double g = 0.5 * (x + 1.0);
    for (int i = 0; i < 40; ++i) {
        double ng = 0.5 * (g + x / g);
        if (ng == g) break;
        g = ng;
    }
    return g * scale;   // scale is a power of two -> exact
}

constexpr Tables make_tables() {
    Tables t{};
    const float beta1 = 1e-4f;
    const float betaT = 0.02f;
    const float delta = (betaT - beta1) / 1000.0f;
    float ac = 1.0f, P = 1.0f, c = 0.0f;
    for (int k = 0; k < T_STEPS; ++k) {
        float beta = beta1 + (float)k * delta;
        ac = ac * (1.0f - beta);
        float s = (float)csqrt_d((double)ac);
        P = P * s;
        c = c * s + beta * beta;
        t.P[k] = P;
        t.C[k] = c;
    }
    return t;
}

__device__ __constant__ Tables d_tbl = make_tables();

// K_coef: one thread per image; all scattered table gathers live here, once.
__global__ __launch_bounds__(256) void coef_kernel(
    const int* __restrict__ tsteps,
    float2*    __restrict__ coef)
{
    const int i = blockIdx.x * 256 + threadIdx.x;   // 0..8191
    const int t = tsteps[i] - 1;                    // in [0, 999]
    coef[i] = make_float2(d_tbl.P[t], d_tbl.C[t]);
}

// K_fix: one block = one 32x32 channel (256 f4). RMW on out (L2/L3-warm from
// the blit). img = bid/3 is SGPR math; coef[img] is a wave-uniform s_load.
__global__ __launch_bounds__(256) void fixup_kernel(
    const float*  __restrict__ nrm,
    const float2* __restrict__ coef,
    float*        __restrict__ out)
{
    const int bid = blockIdx.x;
    const int img = __builtin_amdgcn_readfirstlane(bid / 3);
    const float2 pc = coef[img];                    // {Pt, Ct}, scalar load

    const int tid = threadIdx.x;
    const int f   = bid * 256 + tid;                // global f4 index

    // Diagonal geometry: within-channel f4 index == tid.
    const int h  = tid >> 3;
    const int w0 = (tid & 7) << 2;
    const int d  = h - w0;
    const bool has_diag = (unsigned)d < 4u;

    float4 v = reinterpret_cast<float4*>(out)[f];   // L2/L3 hit (just blitted)
    float nv = 0.0f;
    if (has_diag) nv = nrm[(f << 2) + d];

    float4 r;
    r.x = v.x * pc.x + (d == 0 ? nv * pc.y : 0.0f);
    r.y = v.y * pc.x + (d == 1 ? nv * pc.y : 0.0f);
    r.z = v.z * pc.x + (d == 2 ? nv * pc.y : 0.0f);
    r.w = v.w * pc.x + (d == 3 ? nv * pc.y : 0.0f);
    reinterpret_cast<float4*>(out)[f] = r;
}

extern "C" void kernel_launch(void* const* d_in, const int* in_sizes, int n_in,
                              void* d_out, int out_size, void* d_ws, size_t ws_size,
                              hipStream_t stream) {
    const float* x0     = (const float*)d_in[0];
    const float* nrm    = (const float*)d_in[1];
    const int*   tsteps = (const int*)d_in[2];
    float*       out    = (float*)d_out;
    float2*      coef   = (float2*)d_ws;            // 8192 * 8 B = 64 KB

    coef_kernel<<<COEF_BLOCKS, 256, 0, stream>>>(tsteps, coef);
    hipMemcpyAsync(out, x0, N_BYTES, hipMemcpyDeviceToDevice, stream);
    fixup_kernel<<<FIX_BLOCKS, 256, 0, stream>>>(nrm, coef, out);
}